// Round 8
// baseline (751.156 us; speedup 1.0000x reference)
//
#include <hip/hip_runtime.h>
#include <math.h>

#define NEG_SLOPE 0.2f

typedef __attribute__((ext_vector_type(8))) short short8;
typedef __attribute__((ext_vector_type(4))) float floatx4;

// ---------------- fp32 <-> bf16 split helpers (RNE) ----------------
__device__ __forceinline__ unsigned short f2bf(float f) {
    unsigned u = __float_as_uint(f);
    u += 0x7fffu + ((u >> 16) & 1u);
    return (unsigned short)(u >> 16);
}
__device__ __forceinline__ float bf2f(unsigned short h) {
    return __uint_as_float((unsigned)h << 16);
}
__device__ __forceinline__ float lrelu(float v) {
    return v > 0.f ? v : NEG_SLOPE * v;
}

// ---- async global->LDS, 16B per lane (gfx950). dest = uniform base + lane*16
typedef __attribute__((address_space(3))) unsigned int lds_u32;
typedef const __attribute__((address_space(1))) unsigned int glb_u32c;
__device__ __forceinline__ void gll16(const unsigned short* g, unsigned short* l) {
    __builtin_amdgcn_global_load_lds((glb_u32c*)g, (lds_u32*)l, 16, 0, 0);
}

// ---------------- fused weight pre-pass: 8 jobs in one launch ----------------
struct SJob { const float* W; unsigned short* Th; unsigned short* Tl; int K, N, Kp, base; };
struct SJobs { SJob j[8]; };

__global__ __launch_bounds__(256) void split_transpose_multi(SJobs js) {
    int t = blockIdx.x;
    int ji = 0;
#pragma unroll
    for (int q = 1; q < 8; ++q) if (t >= js.j[q].base) ji = q;
    const SJob jb = js.j[ji];
    int local = t - jb.base;
    int ntiles = jb.N / 32;
    int tn = local % ntiles, tk = local / ntiles;
    int k0 = tk * 32, n0 = tn * 32;
    __shared__ float tbuf[32][33];
    int c = threadIdx.x & 31, r = threadIdx.x >> 5;
    for (int rr = r; rr < 32; rr += 8) {
        int k = k0 + rr, n = n0 + c;
        tbuf[rr][c] = (k < jb.K && n < jb.N) ? jb.W[(long)k * jb.N + n] : 0.f;
    }
    __syncthreads();
    for (int rr = r; rr < 32; rr += 8) {
        int n = n0 + rr, k = k0 + c;
        if (n < jb.N && k < jb.Kp) {
            float v = tbuf[c][rr];
            unsigned short h = f2bf(v);
            jb.Th[(long)n * jb.Kp + k] = h;
            jb.Tl[(long)n * jb.Kp + k] = f2bf(v - bf2f(h));
        }
    }
}

// ---- cell_x row split: [M][735] fp32 -> [M][736] bf16 hi/lo (zero-pad) ----
__global__ __launch_bounds__(256) void split_cell_rows(
    const float* __restrict__ X, unsigned short* __restrict__ H,
    unsigned short* __restrict__ L, int M)
{
    long i = blockIdx.x;
    int t = threadIdx.x;
    const float* r = X + i * 735;
    for (int c = t; c < 736; c += 256) {
        float v = (c < 735) ? r[c] : 0.f;
        unsigned short h = f2bf(v);
        H[i * 736 + c] = h;
        L[i * 736 + c] = f2bf(v - bf2f(h));
    }
}

// ---- 4 fused matvecs: wa[k] = sum_n W[k][n]*a[n] (k in [0,256) each) ----
__global__ __launch_bounds__(256) void matvec4(
    const float* __restrict__ gdW, const float* __restrict__ gdas, const float* __restrict__ gdad,
    float* __restrict__ wds, float* __restrict__ wdd,
    const float* __restrict__ g1W, const float* __restrict__ g1as, const float* __restrict__ g1ad,
    float* __restrict__ w1s, float* __restrict__ w1d)
{
    int b = blockIdx.x;
    int sel = b >> 8, k = b & 255, t = threadIdx.x;
    const float *W, *a; float* o; int N;
    if (sel == 0)      { W = gdW; a = gdas; o = wds; N = 256; }
    else if (sel == 1) { W = gdW; a = gdad; o = wdd; N = 256; }
    else if (sel == 2) { W = g1W; a = g1as; o = w1s; N = 1024; }
    else               { W = g1W; a = g1ad; o = w1d; N = 1024; }
    float s = 0.f;
    for (int n = t; n < N; n += 256) s += W[(long)k * N + n] * a[n];
#pragma unroll
    for (int off = 32; off; off >>= 1) s += __shfl_down(s, off);
    __shared__ float ls[4];
    if ((t & 63) == 0) ls[t >> 6] = s;
    __syncthreads();
    if (t == 0) o[k] = ls[0] + ls[1] + ls[2] + ls[3];
}

// ======== dedicated d0 kernel: M x 128 @ 128 x 256, no LDS, no barriers ======
__global__ __launch_bounds__(256, 3) void gemm_d0_fused(
    const float* __restrict__ A,                    // [M][128] fp32
    const unsigned short* __restrict__ Bh_g,        // [256][128] bf16-hi
    const unsigned short* __restrict__ Bl_g,        // [256][128] bf16-lo
    const float* __restrict__ bias,                 // [256]
    const float* __restrict__ was, const float* __restrict__ wad, // [256]
    float* __restrict__ C,                          // [M][256] fp32 (relu'd)
    float* __restrict__ das, float* __restrict__ dad,
    int M, int nblk)
{
    int bid = blockIdx.x;
    int q = nblk >> 3, rr = nblk & 7;
    int xcd = bid & 7, idx = bid >> 3;
    int wg = (xcd < rr ? xcd * (q + 1) : rr * (q + 1) + (xcd - rr) * q) + idx;
    int rb = wg >> 1, colh = wg & 1;
    int m0 = rb * 64, n0 = colh * 128;
    if (m0 >= M) return;
    const int tid = threadIdx.x;
    const int wave = tid >> 6, lane = tid & 63;
    const int lm = lane & 15, lq = lane >> 4;
    const int wn = n0 + wave * 32;

    floatx4 acc[4][2];
    floatx4 zero = {0.f, 0.f, 0.f, 0.f};
#pragma unroll
    for (int i = 0; i < 4; ++i)
#pragma unroll
        for (int j = 0; j < 2; ++j) acc[i][j] = zero;

#pragma unroll
    for (int ks = 0; ks < 4; ++ks) {
        const int kc = ks * 32 + lq * 8;
        short8 bh[2], bl[2];
#pragma unroll
        for (int j = 0; j < 2; ++j) {
            long bo = (long)(wn + j * 16 + lm) * 128 + kc;
            bh[j] = *(const short8*)(Bh_g + bo);
            bl[j] = *(const short8*)(Bl_g + bo);
        }
        short8 ah[4], al[4];
#pragma unroll
        for (int i = 0; i < 4; ++i) {
            int gm = m0 + i * 16 + lm;
            float4 t0 = {0.f, 0.f, 0.f, 0.f}, t1 = {0.f, 0.f, 0.f, 0.f};
            if (gm < M) {
                const float* ap = A + (long)gm * 128 + kc;
                t0 = *(const float4*)ap;
                t1 = *(const float4*)(ap + 4);
            }
            short8 h, l;
            float f;
            f = t0.x; h[0] = f2bf(f); l[0] = f2bf(f - bf2f(h[0]));
            f = t0.y; h[1] = f2bf(f); l[1] = f2bf(f - bf2f(h[1]));
            f = t0.z; h[2] = f2bf(f); l[2] = f2bf(f - bf2f(h[2]));
            f = t0.w; h[3] = f2bf(f); l[3] = f2bf(f - bf2f(h[3]));
            f = t1.x; h[4] = f2bf(f); l[4] = f2bf(f - bf2f(h[4]));
            f = t1.y; h[5] = f2bf(f); l[5] = f2bf(f - bf2f(h[5]));
            f = t1.z; h[6] = f2bf(f); l[6] = f2bf(f - bf2f(h[6]));
            f = t1.w; h[7] = f2bf(f); l[7] = f2bf(f - bf2f(h[7]));
            ah[i] = h; al[i] = l;
        }
#pragma unroll
        for (int i = 0; i < 4; ++i)
#pragma unroll
            for (int j = 0; j < 2; ++j) {
                acc[i][j] = __builtin_amdgcn_mfma_f32_16x16x32_bf16(ah[i], bh[j], acc[i][j], 0, 0, 0);
                acc[i][j] = __builtin_amdgcn_mfma_f32_16x16x32_bf16(al[i], bh[j], acc[i][j], 0, 0, 0);
                acc[i][j] = __builtin_amdgcn_mfma_f32_16x16x32_bf16(ah[i], bl[j], acc[i][j], 0, 0, 0);
            }
    }

    // ---- epilogue: bias+relu, store C, fused att-scalar partials ----
    __shared__ float sps[64][5], spd[64][5];
    float bv[2], wsv[2], wdv[2];
#pragma unroll
    for (int j = 0; j < 2; ++j) {
        int gn = wn + j * 16 + lm;
        bv[j] = bias[gn];
        wsv[j] = was[gn];
        wdv[j] = wad[gn];
    }
#pragma unroll
    for (int i = 0; i < 4; ++i) {
#pragma unroll
        for (int r = 0; r < 4; ++r) {
            int gm = m0 + i * 16 + lq * 4 + r;
            float vs = 0.f, vd = 0.f;
#pragma unroll
            for (int j = 0; j < 2; ++j) {
                int gn = wn + j * 16 + lm;
                float v = fmaxf(acc[i][j][r] + bv[j], 0.f);
                if (gm < M) C[(long)gm * 256 + gn] = v;
                vs = fmaf(v, wsv[j], vs);
                vd = fmaf(v, wdv[j], vd);
            }
#pragma unroll
            for (int o = 8; o; o >>= 1) {
                vs += __shfl_xor(vs, o);
                vd += __shfl_xor(vd, o);
            }
            if (lm == 0) {
                sps[i * 16 + lq * 4 + r][wave] = vs;
                spd[i * 16 + lq * 4 + r][wave] = vd;
            }
        }
    }
    __syncthreads();
    if (tid < 64) {
        int gm = m0 + tid;
        if (gm < M) {
            float s = sps[tid][0] + sps[tid][1] + sps[tid][2] + sps[tid][3];
            float d2 = spd[tid][0] + spd[tid][1] + spd[tid][2] + spd[tid][3];
            atomicAdd(das + gm, s);
            atomicAdd(dad + gm, d2);
        }
    }
}

// ---------------- GEMM via split-bf16 MFMA, 128x128 tile, 512 threads -------
// r6/r8: 2-phase software pipeline (T3 minimum recipe). Double-buffered LDS
// (64KB): issue tile t+1's 4 global_load_lds BEFORE reading/MFMA'ing tile t,
// ONE barrier per K-step (dbuf removes the write-after-read hazard barrier).
template<int ACT, int OSPLIT>  // ACT: 0=none,1=relu,2=elu
__global__ __launch_bounds__(512, 4) void gemm2(
    const unsigned short* __restrict__ Ah_g, const unsigned short* __restrict__ Al_g,
    const unsigned short* __restrict__ Bh_g, const unsigned short* __restrict__ Bl_g,
    const float* __restrict__ bias,
    float* __restrict__ C, unsigned short* __restrict__ Ch_g, unsigned short* __restrict__ Cl_g,
    int M, int K, int N, int Kp, int Cs)
{
    __shared__ unsigned short Ah[2][4096];
    __shared__ unsigned short Al[2][4096];
    __shared__ unsigned short Bh[2][4096];
    __shared__ unsigned short Bl[2][4096];
    const int tid = threadIdx.x;
    const int wave = tid >> 6, lane = tid & 63;
    const int lm = lane & 15, lq = lane >> 4;
    const int wm = (wave & 1) << 6;      // m-half: 0 / 64
    const int wn = (wave >> 1) << 5;     // n-quarter: 0 / 32 / 64 / 96
    // ---- XCD swizzle (bijective over padded grid) ----
    const int nx = gridDim.x;
    const int lin = blockIdx.y * nx + blockIdx.x;
    const int sup = lin / (8 * nx);
    const int wit = lin - sup * 8 * nx;
    const int rowb = sup * 8 + (wit & 7);
    const int nb = wit >> 3;
    const int m0 = rowb * 128, n0 = nb * 128;
    if (m0 >= M) return;   // padded row-band

    floatx4 acc[4][2];
    floatx4 zero = {0.f, 0.f, 0.f, 0.f};
#pragma unroll
    for (int i = 0; i < 4; ++i)
#pragma unroll
        for (int j = 0; j < 2; ++j) acc[i][j] = zero;

    // ---- staging addresses (per-lane source, wave-uniform LDS chunk) ----
    const int srow = lane >> 2;                       // row within 16-row chunk
    const int sslot = (lane & 3) ^ ((lane >> 3) & 3); // pre-swizzled source slot
    const unsigned short* agh = Ah_g + (long)(m0 + wave * 16 + srow) * Kp + sslot * 8;
    const unsigned short* agl = Al_g + (long)(m0 + wave * 16 + srow) * Kp + sslot * 8;
    const unsigned short* bgh = Bh_g + (long)(n0 + wave * 16 + srow) * Kp + sslot * 8;
    const unsigned short* bgl = Bl_g + (long)(n0 + wave * 16 + srow) * Kp + sslot * 8;
    const int wch = wave * 512;
    const int xa = (lm >> 1) & 3;                     // read-side swizzle key

    // prologue: stage tile 0 into buffer 0
    gll16(agh, &Ah[0][wch]);
    gll16(agl, &Al[0][wch]);
    gll16(bgh, &Bh[0][wch]);
    gll16(bgl, &Bl[0][wch]);
    __syncthreads();
    int cur = 0;

    for (int k0 = 0; k0 < K; k0 += 32) {
        // issue next tile's loads into the other buffer (overlaps with MFMA)
        if (k0 + 32 < K) {
            int nxt = cur ^ 1;
            gll16(agh + k0 + 32, &Ah[nxt][wch]);
            gll16(agl + k0 + 32, &Al[nxt][wch]);
            gll16(bgh + k0 + 32, &Bh[nxt][wch]);
            gll16(bgl + k0 + 32, &Bl[nxt][wch]);
        }
        short8 fah[4], fal[4], fbh[2], fbl[2];
#pragma unroll
        for (int i = 0; i < 4; ++i) {
            int off = (wm + i * 16 + lm) * 32 + ((lq ^ xa) << 3);
            fah[i] = *(const short8*)&Ah[cur][off];
            fal[i] = *(const short8*)&Al[cur][off];
        }
#pragma unroll
        for (int j = 0; j < 2; ++j) {
            int off = (wn + j * 16 + lm) * 32 + ((lq ^ xa) << 3);
            fbh[j] = *(const short8*)&Bh[cur][off];
            fbl[j] = *(const short8*)&Bl[cur][off];
        }
#pragma unroll
        for (int i = 0; i < 4; ++i)
#pragma unroll
            for (int j = 0; j < 2; ++j) {
                acc[i][j] = __builtin_amdgcn_mfma_f32_16x16x32_bf16(fah[i], fbh[j], acc[i][j], 0, 0, 0);
                acc[i][j] = __builtin_amdgcn_mfma_f32_16x16x32_bf16(fal[i], fbh[j], acc[i][j], 0, 0, 0);
                acc[i][j] = __builtin_amdgcn_mfma_f32_16x16x32_bf16(fah[i], fbl[j], acc[i][j], 0, 0, 0);
            }
        __syncthreads();   // drains next-tile gll; protects buf[cur] for reuse
        cur ^= 1;
    }
    // ---- epilogue: C/D layout col=lane&15, row=quad*4+reg (m89-verified) ----
#pragma unroll
    for (int j = 0; j < 2; ++j) {
        int gn = n0 + wn + j * 16 + lm;
        float bv = bias ? bias[gn] : 0.f;
#pragma unroll
        for (int i = 0; i < 4; ++i) {
#pragma unroll
            for (int r = 0; r < 4; ++r) {
                int gm = m0 + wm + i * 16 + lq * 4 + r;
                if (gm < M) {
                    float v = acc[i][j][r] + bv;
                    if (ACT == 1) v = fmaxf(v, 0.f);
                    if (ACT == 2) v = v > 0.f ? v : expm1f(v);
                    if (OSPLIT) {
                        long o = (long)gm * Cs + gn;
                        unsigned short h = f2bf(v);
                        Ch_g[o] = h;
                        Cl_g[o] = f2bf(v - bf2f(h));
                    } else {
                        C[(long)gm * (long)Cs + gn] = v;
                    }
                }
            }
        }
    }
}

// ---------------- per-node attention scalars (F=256) ----------------
__global__ __launch_bounds__(256) void att_scalars(
    const float* __restrict__ x, const float* __restrict__ avs,
    const float* __restrict__ avd, float* __restrict__ outs,
    float* __restrict__ outd, int F)
{
    const int i = blockIdx.x;
    const int t = threadIdx.x;
    float ps = 0.f, pd = 0.f;
    for (int f = t; f < F; f += 256) {
        float v = x[(long)i * F + f];
        ps += v * avs[f];
        pd += v * avd[f];
    }
#pragma unroll
    for (int off = 32; off; off >>= 1) {
        ps += __shfl_down(ps, off);
        pd += __shfl_down(pd, off);
    }
    __shared__ float ls[4], ld[4];
    int lane = t & 63, w = t >> 6;
    if (lane == 0) { ls[w] = ps; ld[w] = pd; }
    __syncthreads();
    if (t == 0) {
        outs[i] = ls[0] + ls[1] + ls[2] + ls[3];
        outd[i] = ld[0] + ld[1] + ld[2] + ld[3];
    }
}

// ---------------------------- CSR build (by dst) ----------------------------
__global__ __launch_bounds__(256) void hist_kernel(
    const int* __restrict__ dst, int* __restrict__ cnt, int E, int n)
{
    int t = blockIdx.x * 256 + threadIdx.x;
    if (t >= E + n) return;
    int d = t < E ? dst[t] : (t - E);
    atomicAdd(&cnt[d], 1);
}

// ---- multi-block 3-pass scan ----
__global__ __launch_bounds__(256) void scan1_kernel(
    const int* __restrict__ cnt, int* __restrict__ off,
    int* __restrict__ bsum, int n)
{
    __shared__ int s[256];
    int b = blockIdx.x, t = threadIdx.x, i = b * 256 + t;
    int v = (i < n) ? cnt[i] : 0;
    s[t] = v;
    __syncthreads();
    for (int d = 1; d < 256; d <<= 1) {
        int u = (t >= d) ? s[t - d] : 0;
        __syncthreads();
        s[t] += u;
        __syncthreads();
    }
    if (i < n) off[i] = s[t] - v;     // block-local exclusive
    if (t == 255) bsum[b] = s[255];
}

__global__ __launch_bounds__(256) void scan2_kernel(
    const int* __restrict__ bsum, int* __restrict__ bpre, int nb,
    int* __restrict__ off, int n)
{
    __shared__ int s[256];
    int t = threadIdx.x;
    int v = (t < nb) ? bsum[t] : 0;
    s[t] = v;
    __syncthreads();
    for (int d = 1; d < 256; d <<= 1) {
        int u = (t >= d) ? s[t - d] : 0;
        __syncthreads();
        s[t] += u;
        __syncthreads();
    }
    if (t < nb) bpre[t] = s[t] - v;
    if (t == 255) off[n] = s[255];
}

__global__ __launch_bounds__(256) void scan3_kernel(
    int* __restrict__ off, int* __restrict__ cursor,
    const int* __restrict__ bpre, int n)
{
    int i = blockIdx.x * 256 + threadIdx.x;
    if (i < n) {
        int v = off[i] + bpre[blockIdx.x];
        off[i] = v;
        cursor[i] = v;
    }
}

__global__ __launch_bounds__(256) void scatter_kernel(
    const int* __restrict__ src, const int* __restrict__ dst,
    int* __restrict__ cursor, int* __restrict__ ebuf, int E, int n)
{
    int t = blockIdx.x * 256 + threadIdx.x;
    if (t >= E + n) return;
    int s = t < E ? src[t] : (t - E);
    int d = t < E ? dst[t] : (t - E);
    int pos = atomicAdd(&cursor[d], 1);
    ebuf[pos] = s;
}

// ------------- fused softmax + aggregate, F=256 fixed -----------------------
template<int EPI>
__global__ __launch_bounds__(256) void gat_agg2(
    const int* __restrict__ off, const int* __restrict__ ebuf,
    const float* __restrict__ as_, const float* __restrict__ ad_,
    const float* __restrict__ x, const float* __restrict__ bias,
    const int* __restrict__ dmap,
    float* __restrict__ outF, unsigned short* __restrict__ outH,
    unsigned short* __restrict__ outL)
{
    __shared__ float sacc[4][256];
    __shared__ int   sS[128];
    __shared__ float sE[128];
    __shared__ float sred[8];
    int d = dmap ? dmap[blockIdx.x] : blockIdx.x;
    int tid = threadIdx.x;
    int w = tid >> 6, lane = tid & 63;
    int lo = off[d], hi = off[d + 1], ne = hi - lo;
    float adv = ad_[d];
    const float* xb = x + lane * 4;
    float4 acc0 = {0.f, 0.f, 0.f, 0.f}, acc1 = {0.f, 0.f, 0.f, 0.f};
    float psum = 0.f;

    if (ne <= 128) {
        if (tid < ne) {
            int s = ebuf[lo + tid];
            sS[tid] = s;
            sE[tid] = lrelu(as_[s] + adv);
        }
        __syncthreads();
        float m = (tid < ne) ? sE[tid] : -INFINITY;
#pragma unroll
        for (int o = 32; o; o >>= 1) m = fmaxf(m, __shfl_xor(m, o));
        if (lane == 0) sred[w] = m;
        __syncthreads();
        m = fmaxf(fmaxf(sred[0], sred[1]), fmaxf(sred[2], sred[3]));
        if (tid < ne) sE[tid] = expf(sE[tid] - m);
        __syncthreads();
        int i = w;
        for (; i + 4 < ne; i += 8) {
            int s0 = sS[i], s1 = sS[i + 4];
            float e0 = sE[i], e1 = sE[i + 4];
            float4 v0 = *(const float4*)(xb + (long)s0 * 256);
            float4 v1 = *(const float4*)(xb + (long)s1 * 256);
            psum += e0; psum += e1;
            acc0.x = fmaf(e0, v0.x, acc0.x); acc0.y = fmaf(e0, v0.y, acc0.y);
            acc0.z = fmaf(e0, v0.z, acc0.z); acc0.w = fmaf(e0, v0.w, acc0.w);
            acc1.x = fmaf(e1, v1.x, acc1.x); acc1.y = fmaf(e1, v1.y, acc1.y);
            acc1.z = fmaf(e1, v1.z, acc1.z); acc1.w = fmaf(e1, v1.w, acc1.w);
        }
        if (i < ne) {
            int s0 = sS[i];
            float e0 = sE[i];
            float4 v0 = *(const float4*)(xb + (long)s0 * 256);
            psum += e0;
            acc0.x = fmaf(e0, v0.x, acc0.x); acc0.y = fmaf(e0, v0.y, acc0.y);
            acc0.z = fmaf(e0, v0.z, acc0.z); acc0.w = fmaf(e0, v0.w, acc0.w);
        }
    } else {
        float m = -INFINITY;
        for (int p = lo + tid; p < hi; p += 256)
            m = fmaxf(m, lrelu(as_[ebuf[p]] + adv));
#pragma unroll
        for (int o = 32; o; o >>= 1) m = fmaxf(m, __shfl_xor(m, o));
        if (lane == 0) sred[w] = m;
        __syncthreads();
        m = fmaxf(fmaxf(sred[0], sred[1]), fmaxf(sred[2], sred[3]));
        for (int c = lo; c < hi; c += 128) {
            int cn = min(128, hi - c);
            __syncthreads();
            if (tid < cn) {
                int s = ebuf[c + tid];
                sS[tid] = s;
                sE[tid] = expf(lrelu(as_[s] + adv) - m);
            }
            __syncthreads();
            int i = w;
            for (; i + 4 < cn; i += 8) {
                int s0 = sS[i], s1 = sS[i + 4];
                float e0 = sE[i], e1 = sE[i + 4];
                float4 v0 = *(const float4*)(xb + (long)s0 * 256);
                float4 v1 = *(const float4*)(xb + (long)s1 * 256);
                psum += e0; psum += e1;
                acc0.x = fmaf(e0, v0.x, acc0.x); acc0.y = fmaf(e0, v0.y, acc0.y);
                acc0.z = fmaf(e0, v0.z, acc0.z); acc0.w = fmaf(e0, v0.w, acc0.w);
                acc1.x = fmaf(e1, v1.x, acc1.x); acc1.y = fmaf(e1, v1.y, acc1.y);
                acc1.z = fmaf(e1, v1.z, acc1.z); acc1.w = fmaf(e1, v1.w, acc1.w);
            }
            if (i < cn) {
                int s0 = sS[i];
                float e0 = sE[i];
                float4 v0 = *(const float4*)(xb + (long)s0 * 256);
                psum += e0;
                acc0.x = fmaf(e0, v0.x, acc0.x); acc0.y = fmaf(e0, v0.y, acc0.y);
                acc0.z = fmaf(e0, v0.z, acc0.z); acc0.w = fmaf(e0, v0.w, acc0.w);
            }
        }
    }
    acc0.x += acc1.x; acc0.y += acc1.y; acc0.z += acc1.z; acc0.w += acc1.w;
    if (lane == 0) sred[4 + w] = psum;
    *(float4*)&sacc[w][lane * 4] = acc0;
    __syncthreads();
    float inv = 1.f / (sred[4] + sred[5] + sred[6] + sred[7]);
    float v = (sacc[0][tid] + sacc[1][tid] + sacc[2][tid] + sacc[3][tid]) * inv;
    long o = (long)blockIdx.x * 256 + tid;
    if (EPI == 1) {
        outF[o] = fmaxf(v + bias[tid], 0.f);
    } else {
        unsigned short h = f2bf(v);
        outH[o] = h;
        outL[o] = f2bf(v - bf2f(h));
    }
}

// comb right half: comb[i][256+t] = split(cfin[cidx[i]][t])
__global__ __launch_bounds__(256) void gather_cell_split(
    const float* __restrict__ cfin, const int* __restrict__ cidx,
    unsigned short* __restrict__ combH, unsigned short* __restrict__ combL)
{
    int i = blockIdx.x;
    int t = threadIdx.x;
    float v = cfin[(long)cidx[i] * 256 + t];
    long b = (long)i * 512 + 256 + t;
    unsigned short h = f2bf(v);
    combH[b] = h;
    combL[b] = f2bf(v - bf2f(h));
}

// out[i] = h[i] . w + b[0]
__global__ __launch_bounds__(256) void head_final_kernel(
    const float* __restrict__ h, const float* __restrict__ w,
    const float* __restrict__ b, float* __restrict__ out, int M)
{
    int gw = blockIdx.x * 4 + (threadIdx.x >> 6);
    int lane = threadIdx.x & 63;
    if (gw >= M) return;
    const float* row = h + (long)gw * 512;
    float s = 0.f;
#pragma unroll
    for (int f = lane; f < 512; f += 64) s += row[f] * w[f];
#pragma unroll
    for (int off = 32; off; off >>= 1) s += __shfl_down(s, off);
    if (lane == 0) out[gw] = s + b[0];
}

// ------------------------------ orchestration -------------------------------
static inline dim3 mfma_grid(int M, int N) {
    int ny = (M + 127) / 128;
    ny = (ny + 7) & ~7;
    return dim3(N / 128, ny);
}

extern "C" void kernel_launch(void* const* d_in, const int* in_sizes, int n_in,
                              void* d_out, int out_size, void* d_ws, size_t ws_size,
                              hipStream_t stream)
{
    const float* drug_x = (const float*)d_in[0];
    const float* cell_x = (const float*)d_in[1];
    const int* d_ei = (const int*)d_in[2];
    const int* c_ei = (const int*)d_in[3];
    const int* d_idx = (const int*)d_in[4];
    const int* c_idx = (const int*)d_in[5];
    const float* dW1 = (const float*)d_in[6];
    const float* db1 = (const float*)d_in[7];
    const float* cW1 = (const float*)d_in[8];
    const float* cb1 = (const float*)d_in[9];
    const float* cW2 = (const float*)d_in[10];
    const float* cb2 = (const float*)d_in[11];
    const float* gdW = (const float*)d_in[12];
    const float* gdas = (const float*)d_in[13];
    const float* gdad = (const float*)d_in[14];
    const float* gdb = (const float*)d_in[15];
    const float* g1W = (const float*)d_in[16];
    const float* g1as = (const float*)d_in[17];
    const float* g1ad = (const float*)d_in[18];
    const float* g1b = (const float*)d_in[19];
    const float* g2W = (const float*)d_in[20];
    const float* g2as = (const float*)d_in[21];
    const float* g2ad = (const float*)d_in[22];
    const float* g2b = (const float*)d_in[23];
    const float* rW1 = (const float*)d_in[24];
    const float* rb1 = (const float*)d_in[25];
    const float* rW2 = (const float*)d_in[26];
    const float* rb2 = (const float*)d_in[27];
    const float* rW3 = (const float*)d_in[28];
    const float* rb3 = (const float*)d_in[29];

    const int ND = in_sizes[0] / 128;     // 50000
    const int NC = in_sizes[1] / 735;     // 10000
    const int ED = in_sizes[2] / 2;       // 800000
    const int EC = in_sizes[3] / 2;       // 160000
    const int NB = in_sizes[4];           // 16384

    const int* d_src = d_ei;
    const int* d_dst = d_ei + ED;
    const int* c_src = c_ei;
    const int* c_dst = c_ei + EC;

    const size_t MB = 1ull << 20;
    const size_t KB = 1024;
    char* ws = (char*)d_ws;

    // ---- weight split region [0, 9MB) ----
    size_t wo = 0;
    auto walloc = [&](size_t elems) -> unsigned short* {
        unsigned short* p = (unsigned short*)(ws + wo);
        wo += ((elems * 2 + 255) & ~(size_t)255);
        return p;
    };
    unsigned short* dW1h = walloc(256 * 128);  unsigned short* dW1l = walloc(256 * 128);
    unsigned short* cW1h = walloc(1024 * 736); unsigned short* cW1l = walloc(1024 * 736);
    unsigned short* cW2h = walloc(256 * 1024); unsigned short* cW2l = walloc(256 * 1024);
    unsigned short* gdWh = walloc(256 * 256);  unsigned short* gdWl = walloc(256 * 256);
    unsigned short* g1Wh = walloc(1024 * 256); unsigned short* g1Wl = walloc(1024 * 256);
    unsigned short* g2Wh = walloc(256 * 1024); unsigned short* g2Wl = walloc(256 * 1024);
    unsigned short* rW1h = walloc(512 * 512);  unsigned short* rW1l = walloc(512 * 512);
    unsigned short* rW2h = walloc(512 * 512);  unsigned short* rW2l = walloc(512 * 512);

    // ---- small scratch [9, 16MB) ----
    float* wa_ds  = (float*)(ws + 9 * MB);
    float* wa_dd  = (float*)(ws + 9 * MB + 4 * KB);
    float* wa_c1s = (float*)(ws + 9 * MB + 8 * KB);
    float* wa_c1d = (float*)(ws + 9 * MB + 12 * KB);
    float* cas    = (float*)(ws + 9 * MB + 64 * KB);
    float* cad    = (float*)(ws + 9 * MB + 128 * KB);
    int*   coff   = (int*)(ws + 9 * MB + 192 * KB);
    int*   ccur   = (int*)(ws + 9 * MB + 256 * KB);
    int*   ccnt   = (int*)(ws + 9 * MB + 320 * KB);
    int*   bsum_d = (int*)(ws + 9 * MB + 400 * KB);   // 196 ints
    int*   bpre_d = (int*)(ws + 9 * MB + 404 * KB);
    int*   bsum_c = (int*)(ws + 9 * MB + 408 * KB);   // 40 ints
    int*   bpre_c = (int*)(ws + 9 * MB + 412 * KB);
    int*   cebuf  = (int*)(ws + 10 * MB);              // EC+NC ints
    float* das    = (float*)(ws + 11 * MB);
    float* dad    = (float*)(ws + 11 * MB + 256 * KB);
    int*   doff   = (int*)(ws + 11 * MB + 512 * KB);
    int*   dcur   = (int*)(ws + 11 * MB + 768 * KB);
    int*   dcnt   = (int*)(ws + 12 * MB);
    int*   debuf  = (int*)(ws + 12 * MB + 256 * KB);   // ED+ND ints -> ends ~15.7MB

    // ---- big buffers (liveness-checked) ----
    float* dbuf  = (float*)(ws + 16 * MB);                    // d0 [ND,256] [16,65)
    unsigned short* aggdh = (unsigned short*)(ws + 66 * MB);  // [NB,256] [66,74)
    unsigned short* aggdl = (unsigned short*)(ws + 75 * MB);  // [75,83)
    unsigned short* combh = (unsigned short*)(ws + 84 * MB);  // [NB,512] [84,100)
    unsigned short* combl = (unsigned short*)(ws + 101 * MB); // [101,117)
    unsigned short* c0h = (unsigned short*)(ws + 16 * MB);    // [10112,1024] [16,36)  (dbuf dead)
    unsigned short* c0l = (unsigned short*)(ws + 36 * MB);    // [36,56)
    float* c1b   = (float*)(ws + 118 * MB);                   // [NC,256] [118,128)
    unsigned short* aggch = (unsigned short*)(ws + 129 * MB); // [10112,256] [129,134.1)
    unsigned short* aggcl = (unsigned short*)(ws + 135 * MB); // [135,140.1)
    unsigned short* c2h = (unsigned short*)(ws + 16 * MB);    // [16,36)  (c0 dead)
    unsigned short* c2l = (unsigned short*)(ws + 36 * MB);    // [36,56)
    float* xc2   = (float*)(ws + 118 * MB);                   // [118,128) (c1 dead)
    float* cfin  = (float*)(ws + 141 * MB);                   // [141,151)
    unsigned short* h1h = (unsigned short*)(ws + 16 * MB);    // [NB,512] [16,32) (c2 dead)
    unsigned short* h1l = (unsigned short*)(ws + 33 * MB);    // [33,49)
    float* h2b   = (float*)(ws + 50 * MB);                    // [NB,512] fp32 [50,82)
    // cell_x split planes [NC pad 10112][736]
    unsigned short* cxh = (unsigned short*)(ws + 152 * MB);   // [152,166.9)
    unsigned short* cxl = (unsigned short*)(ws + 167 * MB);   // [167,181.9)

    // ================= fused prepass: 8 splits + 4 matvecs ===================
    SJobs js;
    js.j[0] = {dW1, dW1h, dW1l, 128, 256, 128, 0};
    js.j[1] = {cW1, cW1h, cW1l, 735, 1024, 736, 32};
    js.j[2] = {cW2, cW2h, cW2l, 1024, 256, 1024, 768};
    js.j[3] = {gdW, gdWh, gdWl, 256, 256, 256, 1024};
    js.j[4] = {g1W, g1Wh, g1Wl, 256, 1024, 256, 1088};
    js.j[5] = {g2W, g2Wh, g2Wl, 1024, 256, 1024, 1344};
    js.j[6] = {rW1, rW1h, rW1l, 512, 512, 512, 1600};
    js.j[7] = {rW2, rW2h, rW2l, 512, 512, 512, 1856};
    split_transpose_multi<<<2112, 256, 0, stream>>>(js);
    split_cell_rows<<<NC, 256, 0, stream>>>(cell_x, cxh, cxl, NC);
    matvec4<<<1024, 256, 0, stream>>>(gdW, gdas, gdad, wa_ds, wa_dd,
                                      g1W, g1as, g1ad, wa_c1s, wa_c1d);

    // ======================= drug path (batch-sparse) =======================
    hipMemsetAsync(das, 0, (size_t)ND * 4, stream);
    hipMemsetAsync(dad, 0, (size_t)ND * 4, stream);
    {
        int nblk = 2 * ((ND + 63) / 64);
        gemm_d0_fused<<<nblk, 256, 0, stream>>>(
            drug_x, dW1h, dW1l, db1, wa_ds, wa_dd, dbuf, das, dad, ND, nblk);
    }
    hipMemsetAsync(dcnt, 0, (size_t)ND * 4, stream);
    {
        int tot = ED + ND;
        int nbd = (ND + 255) / 256;
        hist_kernel<<<(tot + 255) / 256, 256, 0, stream>>>(d_dst, dcnt, ED, ND);
        scan1_kernel<<<nbd, 256, 0, stream>>>(dcnt, doff, bsum_d, ND);
        scan2_kernel<<<1, 256, 0, stream>>>(bsum_d, bpre_d, nbd, doff, ND);
        scan3_kernel<<<nbd, 256, 0, stream>>>(doff, dcur, bpre_d, ND);
        scatter_kernel<<<(tot + 255) / 256, 256, 0, stream>>>(d_src, d_dst, dcur, debuf, ED, ND);
        gat_agg2<0><<<NB, 256, 0, stream>>>(doff, debuf, das, dad, dbuf, nullptr,
                                            d_idx, nullptr, aggdh, aggdl);
    }
    // comb left half = relu(aggd_batch @ gdW + gdb) as split planes (stride 512)
    gemm2<1, 1><<<mfma_grid(NB, 256), 512, 0, stream>>>(
        aggdh, aggdl, gdWh, gdWl, gdb, nullptr, combh, combl,
        NB, 256, 256, 256, 512);

    // ======================= cell path =======================
    gemm2<1, 1><<<mfma_grid(NC, 1024), 512, 0, stream>>>(
        cxh, cxl, cW1h, cW1l, cb1, nullptr, c0h, c0l,
        NC, 736, 1024, 736, 1024);
    gemm2<1, 0><<<mfma_grid(NC, 256), 512, 0, stream>>>(
        c0h, c0l, cW2h, cW2l, cb2, c1b, nullptr, nullptr,
        NC, 1024, 256, 1024, 256);
    att_scalars<<<NC, 256, 0, stream>>>(c1b, wa_c1s, wa_c1d, cas, cad, 256);
    hipMemsetAsync(ccnt, 0, (size_t)NC * 4, stream);
    {
        int tot = EC + NC;
        int nbc = (NC + 255) / 256;
        hist_kernel<<<(tot + 255) / 256, 256, 0, stream>>>(c_dst, ccnt, EC, NC);
        scan1_kernel<<<nbc, 256, 0, stream>>>(ccnt, coff, bsum_c, NC);
        scan2_kernel<<<1, 256, 0, stream>>>(bsum_c, bpre_c, nbc, coff, NC);
        scan3_kernel<<<nbc, 256, 0, stream>>>(coff, ccur, bpre_c, NC);
        scatter_kernel<<<(tot + 255) / 256, 256, 0, stream>>>(c_src, c_dst, ccur, cebuf, EC, NC);
        gat_agg2<0><<<NC, 256, 0, stream>>>(coff, cebuf, cas, cad, c1b, nullptr,
                                            nullptr, nullptr, aggch, aggcl);
    }
    gemm2<1, 1><<<mfma_grid(NC, 1024), 512, 0, stream>>>(
        aggch, aggcl, g1Wh, g1Wl, g1b, nullptr, c2h, c2l,
        NC, 256, 1024, 256, 1024);
    gemm2<0, 0><<<mfma_grid(NC, 256), 512, 0, stream>>>(
        c2h, c2l, g2Wh, g2Wl, nullptr, xc2, nullptr, nullptr,
        NC, 1024, 256, 1024, 256);
    att_scalars<<<NC, 256, 0, stream>>>(xc2, g2as, g2ad, cas, cad, 256);
    gat_agg2<1><<<NC, 256, 0, stream>>>(coff, cebuf, cas, cad, xc2, g2b,
                                        nullptr, cfin, nullptr, nullptr);

    // ======================= head =======================
    gather_cell_split<<<NB, 256, 0, stream>>>(cfin, c_idx, combh, combl);
    gemm2<2, 1><<<mfma_grid(NB, 512), 512, 0, stream>>>(
        combh, combl, rW1h, rW1l, rb1, nullptr, h1h, h1l,
        NB, 512, 512, 512, 512);
    gemm2<2, 0><<<mfma_grid(NB, 512), 512, 0, stream>>>(
        h1h, h1l, rW2h, rW2l, rb2, h2b, nullptr, nullptr,
        NB, 512, 512, 512, 512);
    head_final_kernel<<<(NB + 3) / 4, 256, 0, stream>>>(h2b, rW3, rb3, (float*)d_out, NB);
}

// Round 9
// 740.288 us; speedup vs baseline: 1.0147x; 1.0147x over previous
//
#include <hip/hip_runtime.h>
#include <math.h>

#define NEG_SLOPE 0.2f

typedef __attribute__((ext_vector_type(8))) short short8;
typedef __attribute__((ext_vector_type(4))) float floatx4;

// ---------------- fp32 <-> bf16 split helpers (RNE) ----------------
__device__ __forceinline__ unsigned short f2bf(float f) {
    unsigned u = __float_as_uint(f);
    u += 0x7fffu + ((u >> 16) & 1u);
    return (unsigned short)(u >> 16);
}
__device__ __forceinline__ float bf2f(unsigned short h) {
    return __uint_as_float((unsigned)h << 16);
}
__device__ __forceinline__ float lrelu(float v) {
    return v > 0.f ? v : NEG_SLOPE * v;
}

// ---- async global->LDS, 16B per lane (gfx950). dest = uniform base + lane*16
typedef __attribute__((address_space(3))) unsigned int lds_u32;
typedef const __attribute__((address_space(1))) unsigned int glb_u32c;
__device__ __forceinline__ void gll16(const unsigned short* g, unsigned short* l) {
    __builtin_amdgcn_global_load_lds((glb_u32c*)g, (lds_u32*)l, 16, 0, 0);
}

// ---------------- fused weight pre-pass: 8 jobs in one launch ----------------
struct SJob { const float* W; unsigned short* Th; unsigned short* Tl; int K, N, Kp, base; };
struct SJobs { SJob j[8]; };

__global__ __launch_bounds__(256) void split_transpose_multi(SJobs js) {
    int t = blockIdx.x;
    int ji = 0;
#pragma unroll
    for (int q = 1; q < 8; ++q) if (t >= js.j[q].base) ji = q;
    const SJob jb = js.j[ji];
    int local = t - jb.base;
    int ntiles = jb.N / 32;
    int tn = local % ntiles, tk = local / ntiles;
    int k0 = tk * 32, n0 = tn * 32;
    __shared__ float tbuf[32][33];
    int c = threadIdx.x & 31, r = threadIdx.x >> 5;
    for (int rr = r; rr < 32; rr += 8) {
        int k = k0 + rr, n = n0 + c;
        tbuf[rr][c] = (k < jb.K && n < jb.N) ? jb.W[(long)k * jb.N + n] : 0.f;
    }
    __syncthreads();
    for (int rr = r; rr < 32; rr += 8) {
        int n = n0 + rr, k = k0 + c;
        if (n < jb.N && k < jb.Kp) {
            float v = tbuf[c][rr];
            unsigned short h = f2bf(v);
            jb.Th[(long)n * jb.Kp + k] = h;
            jb.Tl[(long)n * jb.Kp + k] = f2bf(v - bf2f(h));
        }
    }
}

// ---- cell_x row split: [M][735] fp32 -> [M][736] bf16 hi/lo (zero-pad) ----
__global__ __launch_bounds__(256) void split_cell_rows(
    const float* __restrict__ X, unsigned short* __restrict__ H,
    unsigned short* __restrict__ L, int M)
{
    long i = blockIdx.x;
    int t = threadIdx.x;
    const float* r = X + i * 735;
    for (int c = t; c < 736; c += 256) {
        float v = (c < 735) ? r[c] : 0.f;
        unsigned short h = f2bf(v);
        H[i * 736 + c] = h;
        L[i * 736 + c] = f2bf(v - bf2f(h));
    }
}

// ---- 4 fused matvecs: wa[k] = sum_n W[k][n]*a[n] (k in [0,256) each) ----
__global__ __launch_bounds__(256) void matvec4(
    const float* __restrict__ gdW, const float* __restrict__ gdas, const float* __restrict__ gdad,
    float* __restrict__ wds, float* __restrict__ wdd,
    const float* __restrict__ g1W, const float* __restrict__ g1as, const float* __restrict__ g1ad,
    float* __restrict__ w1s, float* __restrict__ w1d)
{
    int b = blockIdx.x;
    int sel = b >> 8, k = b & 255, t = threadIdx.x;
    const float *W, *a; float* o; int N;
    if (sel == 0)      { W = gdW; a = gdas; o = wds; N = 256; }
    else if (sel == 1) { W = gdW; a = gdad; o = wdd; N = 256; }
    else if (sel == 2) { W = g1W; a = g1as; o = w1s; N = 1024; }
    else               { W = g1W; a = g1ad; o = w1d; N = 1024; }
    float s = 0.f;
    for (int n = t; n < N; n += 256) s += W[(long)k * N + n] * a[n];
#pragma unroll
    for (int off = 32; off; off >>= 1) s += __shfl_down(s, off);
    __shared__ float ls[4];
    if ((t & 63) == 0) ls[t >> 6] = s;
    __syncthreads();
    if (t == 0) o[k] = ls[0] + ls[1] + ls[2] + ls[3];
}

// ======== dedicated d0 kernel: M x 128 @ 128 x 256, no LDS, no barriers ======
__global__ __launch_bounds__(256, 3) void gemm_d0_fused(
    const float* __restrict__ A,                    // [M][128] fp32
    const unsigned short* __restrict__ Bh_g,        // [256][128] bf16-hi
    const unsigned short* __restrict__ Bl_g,        // [256][128] bf16-lo
    const float* __restrict__ bias,                 // [256]
    const float* __restrict__ was, const float* __restrict__ wad, // [256]
    float* __restrict__ C,                          // [M][256] fp32 (relu'd)
    float* __restrict__ das, float* __restrict__ dad,
    int M, int nblk)
{
    int bid = blockIdx.x;
    int q = nblk >> 3, rr = nblk & 7;
    int xcd = bid & 7, idx = bid >> 3;
    int wg = (xcd < rr ? xcd * (q + 1) : rr * (q + 1) + (xcd - rr) * q) + idx;
    int rb = wg >> 1, colh = wg & 1;
    int m0 = rb * 64, n0 = colh * 128;
    if (m0 >= M) return;
    const int tid = threadIdx.x;
    const int wave = tid >> 6, lane = tid & 63;
    const int lm = lane & 15, lq = lane >> 4;
    const int wn = n0 + wave * 32;

    floatx4 acc[4][2];
    floatx4 zero = {0.f, 0.f, 0.f, 0.f};
#pragma unroll
    for (int i = 0; i < 4; ++i)
#pragma unroll
        for (int j = 0; j < 2; ++j) acc[i][j] = zero;

#pragma unroll
    for (int ks = 0; ks < 4; ++ks) {
        const int kc = ks * 32 + lq * 8;
        short8 bh[2], bl[2];
#pragma unroll
        for (int j = 0; j < 2; ++j) {
            long bo = (long)(wn + j * 16 + lm) * 128 + kc;
            bh[j] = *(const short8*)(Bh_g + bo);
            bl[j] = *(const short8*)(Bl_g + bo);
        }
        short8 ah[4], al[4];
#pragma unroll
        for (int i = 0; i < 4; ++i) {
            int gm = m0 + i * 16 + lm;
            float4 t0 = {0.f, 0.f, 0.f, 0.f}, t1 = {0.f, 0.f, 0.f, 0.f};
            if (gm < M) {
                const float* ap = A + (long)gm * 128 + kc;
                t0 = *(const float4*)ap;
                t1 = *(const float4*)(ap + 4);
            }
            short8 h, l;
            float f;
            f = t0.x; h[0] = f2bf(f); l[0] = f2bf(f - bf2f(h[0]));
            f = t0.y; h[1] = f2bf(f); l[1] = f2bf(f - bf2f(h[1]));
            f = t0.z; h[2] = f2bf(f); l[2] = f2bf(f - bf2f(h[2]));
            f = t0.w; h[3] = f2bf(f); l[3] = f2bf(f - bf2f(h[3]));
            f = t1.x; h[4] = f2bf(f); l[4] = f2bf(f - bf2f(h[4]));
            f = t1.y; h[5] = f2bf(f); l[5] = f2bf(f - bf2f(h[5]));
            f = t1.z; h[6] = f2bf(f); l[6] = f2bf(f - bf2f(h[6]));
            f = t1.w; h[7] = f2bf(f); l[7] = f2bf(f - bf2f(h[7]));
            ah[i] = h; al[i] = l;
        }
#pragma unroll
        for (int i = 0; i < 4; ++i)
#pragma unroll
            for (int j = 0; j < 2; ++j) {
                acc[i][j] = __builtin_amdgcn_mfma_f32_16x16x32_bf16(ah[i], bh[j], acc[i][j], 0, 0, 0);
                acc[i][j] = __builtin_amdgcn_mfma_f32_16x16x32_bf16(al[i], bh[j], acc[i][j], 0, 0, 0);
                acc[i][j] = __builtin_amdgcn_mfma_f32_16x16x32_bf16(ah[i], bl[j], acc[i][j], 0, 0, 0);
            }
    }

    // ---- epilogue: bias+relu, store C, fused att-scalar partials ----
    __shared__ float sps[64][5], spd[64][5];
    float bv[2], wsv[2], wdv[2];
#pragma unroll
    for (int j = 0; j < 2; ++j) {
        int gn = wn + j * 16 + lm;
        bv[j] = bias[gn];
        wsv[j] = was[gn];
        wdv[j] = wad[gn];
    }
#pragma unroll
    for (int i = 0; i < 4; ++i) {
#pragma unroll
        for (int r = 0; r < 4; ++r) {
            int gm = m0 + i * 16 + lq * 4 + r;
            float vs = 0.f, vd = 0.f;
#pragma unroll
            for (int j = 0; j < 2; ++j) {
                int gn = wn + j * 16 + lm;
                float v = fmaxf(acc[i][j][r] + bv[j], 0.f);
                if (gm < M) C[(long)gm * 256 + gn] = v;
                vs = fmaf(v, wsv[j], vs);
                vd = fmaf(v, wdv[j], vd);
            }
#pragma unroll
            for (int o = 8; o; o >>= 1) {
                vs += __shfl_xor(vs, o);
                vd += __shfl_xor(vd, o);
            }
            if (lm == 0) {
                sps[i * 16 + lq * 4 + r][wave] = vs;
                spd[i * 16 + lq * 4 + r][wave] = vd;
            }
        }
    }
    __syncthreads();
    if (tid < 64) {
        int gm = m0 + tid;
        if (gm < M) {
            float s = sps[tid][0] + sps[tid][1] + sps[tid][2] + sps[tid][3];
            float d2 = spd[tid][0] + spd[tid][1] + spd[tid][2] + spd[tid][3];
            atomicAdd(das + gm, s);
            atomicAdd(dad + gm, d2);
        }
    }
}

// ---------------- GEMM via split-bf16 MFMA ----------------------------------
// r9: occupancy-first geometry. r8 post-mortem: 8-wave/64KB blocks -> <=2
// blocks/CU, Occupancy ~25%, and the 2-phase dbuf was NULL (reproduced
// m99/m100/m233: 2-phase plateau ~540-600 TF). Escape via TLP (m114/m97):
// 4-wave blocks, 64m x 128n tile, single-buffered 24KB LDS -> 6 blocks/CU
// (24 waves). Per-wave inner loop identical (4x2 frags, 24 MFMA/step);
// 6 gll/wave/step. Swizzle unchanged (r5: measured 0 conflicts):
//   stage: lane l sources col-slot (l&3)^((l>>3)&3) of row chunk+(l>>2)
//   read:  logical slot lq of row r lives at LDS slot lq^((r>>1)&3)
template<int ACT, int OSPLIT>  // ACT: 0=none,1=relu,2=elu
__global__ __launch_bounds__(256, 6) void gemm2(
    const unsigned short* __restrict__ Ah_g, const unsigned short* __restrict__ Al_g,
    const unsigned short* __restrict__ Bh_g, const unsigned short* __restrict__ Bl_g,
    const float* __restrict__ bias,
    float* __restrict__ C, unsigned short* __restrict__ Ch_g, unsigned short* __restrict__ Cl_g,
    int M, int K, int N, int Kp, int Cs)
{
    __shared__ unsigned short Ah[2048];   // [64 rows][32 k]
    __shared__ unsigned short Al[2048];
    __shared__ unsigned short Bh[4096];   // [128 rows][32 k]
    __shared__ unsigned short Bl[4096];
    const int tid = threadIdx.x;
    const int wave = tid >> 6, lane = tid & 63;
    const int lm = lane & 15, lq = lane >> 4;
    const int wn = wave * 32;            // n-quarter within 128-col tile
    // ---- XCD swizzle (bijective over padded grid) ----
    const int nx = gridDim.x;
    const int lin = blockIdx.y * nx + blockIdx.x;
    const int sup = lin / (8 * nx);
    const int wit = lin - sup * 8 * nx;
    const int rowb = sup * 8 + (wit & 7);
    const int nb = wit >> 3;
    const int m0 = rowb * 64, n0 = nb * 128;
    if (m0 >= M) return;   // padded row-band

    floatx4 acc[4][2];
    floatx4 zero = {0.f, 0.f, 0.f, 0.f};
#pragma unroll
    for (int i = 0; i < 4; ++i)
#pragma unroll
        for (int j = 0; j < 2; ++j) acc[i][j] = zero;

    // ---- staging addresses (per-lane source, wave-uniform LDS chunk) ----
    const int srow = lane >> 2;                       // row within 16-row chunk
    const int sslot = (lane & 3) ^ ((lane >> 3) & 3); // pre-swizzled source slot
    const unsigned short* agh = Ah_g + (long)(m0 + wave * 16 + srow) * Kp + sslot * 8;
    const unsigned short* agl = Al_g + (long)(m0 + wave * 16 + srow) * Kp + sslot * 8;
    const unsigned short* bgh0 = Bh_g + (long)(n0 + wave * 32 + srow) * Kp + sslot * 8;
    const unsigned short* bgh1 = Bh_g + (long)(n0 + wave * 32 + 16 + srow) * Kp + sslot * 8;
    const unsigned short* bgl0 = Bl_g + (long)(n0 + wave * 32 + srow) * Kp + sslot * 8;
    const unsigned short* bgl1 = Bl_g + (long)(n0 + wave * 32 + 16 + srow) * Kp + sslot * 8;
    unsigned short* lAh = &Ah[wave * 512];
    unsigned short* lAl = &Al[wave * 512];
    unsigned short* lBh0 = &Bh[wave * 1024];
    unsigned short* lBh1 = &Bh[wave * 1024 + 512];
    unsigned short* lBl0 = &Bl[wave * 1024];
    unsigned short* lBl1 = &Bl[wave * 1024 + 512];
    const int xa = (lm >> 1) & 3;                     // read-side swizzle key

    for (int k0 = 0; k0 < K; k0 += 32) {
        gll16(agh + k0, lAh);
        gll16(agl + k0, lAl);
        gll16(bgh0 + k0, lBh0);
        gll16(bgh1 + k0, lBh1);
        gll16(bgl0 + k0, lBl0);
        gll16(bgl1 + k0, lBl1);
        __syncthreads();
        short8 fah[4], fal[4], fbh[2], fbl[2];
#pragma unroll
        for (int i = 0; i < 4; ++i) {
            int off = (i * 16 + lm) * 32 + ((lq ^ xa) << 3);
            fah[i] = *(const short8*)&Ah[off];
            fal[i] = *(const short8*)&Al[off];
        }
#pragma unroll
        for (int j = 0; j < 2; ++j) {
            int off = (wn + j * 16 + lm) * 32 + ((lq ^ xa) << 3);
            fbh[j] = *(const short8*)&Bh[off];
            fbl[j] = *(const short8*)&Bl[off];
        }
#pragma unroll
        for (int i = 0; i < 4; ++i)
#pragma unroll
            for (int j = 0; j < 2; ++j) {
                acc[i][j] = __builtin_amdgcn_mfma_f32_16x16x32_bf16(fah[i], fbh[j], acc[i][j], 0, 0, 0);
                acc[i][j] = __builtin_amdgcn_mfma_f32_16x16x32_bf16(fal[i], fbh[j], acc[i][j], 0, 0, 0);
                acc[i][j] = __builtin_amdgcn_mfma_f32_16x16x32_bf16(fah[i], fbl[j], acc[i][j], 0, 0, 0);
            }
        __syncthreads();
    }
    // ---- epilogue: C/D layout col=lane&15, row=quad*4+reg (m89-verified) ----
#pragma unroll
    for (int j = 0; j < 2; ++j) {
        int gn = n0 + wn + j * 16 + lm;
        float bv = bias ? bias[gn] : 0.f;
#pragma unroll
        for (int i = 0; i < 4; ++i) {
#pragma unroll
            for (int r = 0; r < 4; ++r) {
                int gm = m0 + i * 16 + lq * 4 + r;
                if (gm < M) {
                    float v = acc[i][j][r] + bv;
                    if (ACT == 1) v = fmaxf(v, 0.f);
                    if (ACT == 2) v = v > 0.f ? v : expm1f(v);
                    if (OSPLIT) {
                        long o = (long)gm * Cs + gn;
                        unsigned short h = f2bf(v);
                        Ch_g[o] = h;
                        Cl_g[o] = f2bf(v - bf2f(h));
                    } else {
                        C[(long)gm * (long)Cs + gn] = v;
                    }
                }
            }
        }
    }
}

// ---------------- per-node attention scalars (F=256) ----------------
__global__ __launch_bounds__(256) void att_scalars(
    const float* __restrict__ x, const float* __restrict__ avs,
    const float* __restrict__ avd, float* __restrict__ outs,
    float* __restrict__ outd, int F)
{
    const int i = blockIdx.x;
    const int t = threadIdx.x;
    float ps = 0.f, pd = 0.f;
    for (int f = t; f < F; f += 256) {
        float v = x[(long)i * F + f];
        ps += v * avs[f];
        pd += v * avd[f];
    }
#pragma unroll
    for (int off = 32; off; off >>= 1) {
        ps += __shfl_down(ps, off);
        pd += __shfl_down(pd, off);
    }
    __shared__ float ls[4], ld[4];
    int lane = t & 63, w = t >> 6;
    if (lane == 0) { ls[w] = ps; ld[w] = pd; }
    __syncthreads();
    if (t == 0) {
        outs[i] = ls[0] + ls[1] + ls[2] + ls[3];
        outd[i] = ld[0] + ld[1] + ld[2] + ld[3];
    }
}

// ---------------------------- CSR build (by dst) ----------------------------
__global__ __launch_bounds__(256) void hist_kernel(
    const int* __restrict__ dst, int* __restrict__ cnt, int E, int n)
{
    int t = blockIdx.x * 256 + threadIdx.x;
    if (t >= E + n) return;
    int d = t < E ? dst[t] : (t - E);
    atomicAdd(&cnt[d], 1);
}

// ---- multi-block 3-pass scan ----
__global__ __launch_bounds__(256) void scan1_kernel(
    const int* __restrict__ cnt, int* __restrict__ off,
    int* __restrict__ bsum, int n)
{
    __shared__ int s[256];
    int b = blockIdx.x, t = threadIdx.x, i = b * 256 + t;
    int v = (i < n) ? cnt[i] : 0;
    s[t] = v;
    __syncthreads();
    for (int d = 1; d < 256; d <<= 1) {
        int u = (t >= d) ? s[t - d] : 0;
        __syncthreads();
        s[t] += u;
        __syncthreads();
    }
    if (i < n) off[i] = s[t] - v;     // block-local exclusive
    if (t == 255) bsum[b] = s[255];
}

__global__ __launch_bounds__(256) void scan2_kernel(
    const int* __restrict__ bsum, int* __restrict__ bpre, int nb,
    int* __restrict__ off, int n)
{
    __shared__ int s[256];
    int t = threadIdx.x;
    int v = (t < nb) ? bsum[t] : 0;
    s[t] = v;
    __syncthreads();
    for (int d = 1; d < 256; d <<= 1) {
        int u = (t >= d) ? s[t - d] : 0;
        __syncthreads();
        s[t] += u;
        __syncthreads();
    }
    if (t < nb) bpre[t] = s[t] - v;
    if (t == 255) off[n] = s[255];
}

__global__ __launch_bounds__(256) void scan3_kernel(
    int* __restrict__ off, int* __restrict__ cursor,
    const int* __restrict__ bpre, int n)
{
    int i = blockIdx.x * 256 + threadIdx.x;
    if (i < n) {
        int v = off[i] + bpre[blockIdx.x];
        off[i] = v;
        cursor[i] = v;
    }
}

__global__ __launch_bounds__(256) void scatter_kernel(
    const int* __restrict__ src, const int* __restrict__ dst,
    int* __restrict__ cursor, int* __restrict__ ebuf, int E, int n)
{
    int t = blockIdx.x * 256 + threadIdx.x;
    if (t >= E + n) return;
    int s = t < E ? src[t] : (t - E);
    int d = t < E ? dst[t] : (t - E);
    int pos = atomicAdd(&cursor[d], 1);
    ebuf[pos] = s;
}

// ------------- fused softmax + aggregate, F=256 fixed -----------------------
template<int EPI>
__global__ __launch_bounds__(256) void gat_agg2(
    const int* __restrict__ off, const int* __restrict__ ebuf,
    const float* __restrict__ as_, const float* __restrict__ ad_,
    const float* __restrict__ x, const float* __restrict__ bias,
    const int* __restrict__ dmap,
    float* __restrict__ outF, unsigned short* __restrict__ outH,
    unsigned short* __restrict__ outL)
{
    __shared__ float sacc[4][256];
    __shared__ int   sS[128];
    __shared__ float sE[128];
    __shared__ float sred[8];
    int d = dmap ? dmap[blockIdx.x] : blockIdx.x;
    int tid = threadIdx.x;
    int w = tid >> 6, lane = tid & 63;
    int lo = off[d], hi = off[d + 1], ne = hi - lo;
    float adv = ad_[d];
    const float* xb = x + lane * 4;
    float4 acc0 = {0.f, 0.f, 0.f, 0.f}, acc1 = {0.f, 0.f, 0.f, 0.f};
    float psum = 0.f;

    if (ne <= 128) {
        if (tid < ne) {
            int s = ebuf[lo + tid];
            sS[tid] = s;
            sE[tid] = lrelu(as_[s] + adv);
        }
        __syncthreads();
        float m = (tid < ne) ? sE[tid] : -INFINITY;
#pragma unroll
        for (int o = 32; o; o >>= 1) m = fmaxf(m, __shfl_xor(m, o));
        if (lane == 0) sred[w] = m;
        __syncthreads();
        m = fmaxf(fmaxf(sred[0], sred[1]), fmaxf(sred[2], sred[3]));
        if (tid < ne) sE[tid] = expf(sE[tid] - m);
        __syncthreads();
        int i = w;
        for (; i + 4 < ne; i += 8) {
            int s0 = sS[i], s1 = sS[i + 4];
            float e0 = sE[i], e1 = sE[i + 4];
            float4 v0 = *(const float4*)(xb + (long)s0 * 256);
            float4 v1 = *(const float4*)(xb + (long)s1 * 256);
            psum += e0; psum += e1;
            acc0.x = fmaf(e0, v0.x, acc0.x); acc0.y = fmaf(e0, v0.y, acc0.y);
            acc0.z = fmaf(e0, v0.z, acc0.z); acc0.w = fmaf(e0, v0.w, acc0.w);
            acc1.x = fmaf(e1, v1.x, acc1.x); acc1.y = fmaf(e1, v1.y, acc1.y);
            acc1.z = fmaf(e1, v1.z, acc1.z); acc1.w = fmaf(e1, v1.w, acc1.w);
        }
        if (i < ne) {
            int s0 = sS[i];
            float e0 = sE[i];
            float4 v0 = *(const float4*)(xb + (long)s0 * 256);
            psum += e0;
            acc0.x = fmaf(e0, v0.x, acc0.x); acc0.y = fmaf(e0, v0.y, acc0.y);
            acc0.z = fmaf(e0, v0.z, acc0.z); acc0.w = fmaf(e0, v0.w, acc0.w);
        }
    } else {
        float m = -INFINITY;
        for (int p = lo + tid; p < hi; p += 256)
            m = fmaxf(m, lrelu(as_[ebuf[p]] + adv));
#pragma unroll
        for (int o = 32; o; o >>= 1) m = fmaxf(m, __shfl_xor(m, o));
        if (lane == 0) sred[w] = m;
        __syncthreads();
        m = fmaxf(fmaxf(sred[0], sred[1]), fmaxf(sred[2], sred[3]));
        for (int c = lo; c < hi; c += 128) {
            int cn = min(128, hi - c);
            __syncthreads();
            if (tid < cn) {
                int s = ebuf[c + tid];
                sS[tid] = s;
                sE[tid] = expf(lrelu(as_[s] + adv) - m);
            }
            __syncthreads();
            int i = w;
            for (; i + 4 < cn; i += 8) {
                int s0 = sS[i], s1 = sS[i + 4];
                float e0 = sE[i], e1 = sE[i + 4];
                float4 v0 = *(const float4*)(xb + (long)s0 * 256);
                float4 v1 = *(const float4*)(xb + (long)s1 * 256);
                psum += e0; psum += e1;
                acc0.x = fmaf(e0, v0.x, acc0.x); acc0.y = fmaf(e0, v0.y, acc0.y);
                acc0.z = fmaf(e0, v0.z, acc0.z); acc0.w = fmaf(e0, v0.w, acc0.w);
                acc1.x = fmaf(e1, v1.x, acc1.x); acc1.y = fmaf(e1, v1.y, acc1.y);
                acc1.z = fmaf(e1, v1.z, acc1.z); acc1.w = fmaf(e1, v1.w, acc1.w);
            }
            if (i < cn) {
                int s0 = sS[i];
                float e0 = sE[i];
                float4 v0 = *(const float4*)(xb + (long)s0 * 256);
                psum += e0;
                acc0.x = fmaf(e0, v0.x, acc0.x); acc0.y = fmaf(e0, v0.y, acc0.y);
                acc0.z = fmaf(e0, v0.z, acc0.z); acc0.w = fmaf(e0, v0.w, acc0.w);
            }
        }
    }
    acc0.x += acc1.x; acc0.y += acc1.y; acc0.z += acc1.z; acc0.w += acc1.w;
    if (lane == 0) sred[4 + w] = psum;
    *(float4*)&sacc[w][lane * 4] = acc0;
    __syncthreads();
    float inv = 1.f / (sred[4] + sred[5] + sred[6] + sred[7]);
    float v = (sacc[0][tid] + sacc[1][tid] + sacc[2][tid] + sacc[3][tid]) * inv;
    long o = (long)blockIdx.x * 256 + tid;
    if (EPI == 1) {
        outF[o] = fmaxf(v + bias[tid], 0.f);
    } else {
        unsigned short h = f2bf(v);
        outH[o] = h;
        outL[o] = f2bf(v - bf2f(h));
    }
}

// comb right half: comb[i][256+t] = split(cfin[cidx[i]][t])
__global__ __launch_bounds__(256) void gather_cell_split(
    const float* __restrict__ cfin, const int* __restrict__ cidx,
    unsigned short* __restrict__ combH, unsigned short* __restrict__ combL)
{
    int i = blockIdx.x;
    int t = threadIdx.x;
    float v = cfin[(long)cidx[i] * 256 + t];
    long b = (long)i * 512 + 256 + t;
    unsigned short h = f2bf(v);
    combH[b] = h;
    combL[b] = f2bf(v - bf2f(h));
}

// out[i] = h[i] . w + b[0]
__global__ __launch_bounds__(256) void head_final_kernel(
    const float* __restrict__ h, const float* __restrict__ w,
    const float* __restrict__ b, float* __restrict__ out, int M)
{
    int gw = blockIdx.x * 4 + (threadIdx.x >> 6);
    int lane = threadIdx.x & 63;
    if (gw >= M) return;
    const float* row = h + (long)gw * 512;
    float s = 0.f;
#pragma unroll
    for (int f = lane; f < 512; f += 64) s += row[f] * w[f];
#pragma unroll
    for (int off = 32; off; off >>= 1) s += __shfl_down(s, off);
    if (lane == 0) out[gw] = s + b[0];
}

// ------------------------------ orchestration -------------------------------
// 64-row bands; ny padded to x8 for the XCD swizzle bijection
static inline dim3 mfma_grid64(int M, int N) {
    int ny = (M + 63) / 64;
    ny = (ny + 7) & ~7;
    return dim3(N / 128, ny);
}

extern "C" void kernel_launch(void* const* d_in, const int* in_sizes, int n_in,
                              void* d_out, int out_size, void* d_ws, size_t ws_size,
                              hipStream_t stream)
{
    const float* drug_x = (const float*)d_in[0];
    const float* cell_x = (const float*)d_in[1];
    const int* d_ei = (const int*)d_in[2];
    const int* c_ei = (const int*)d_in[3];
    const int* d_idx = (const int*)d_in[4];
    const int* c_idx = (const int*)d_in[5];
    const float* dW1 = (const float*)d_in[6];
    const float* db1 = (const float*)d_in[7];
    const float* cW1 = (const float*)d_in[8];
    const float* cb1 = (const float*)d_in[9];
    const float* cW2 = (const float*)d_in[10];
    const float* cb2 = (const float*)d_in[11];
    const float* gdW = (const float*)d_in[12];
    const float* gdas = (const float*)d_in[13];
    const float* gdad = (const float*)d_in[14];
    const float* gdb = (const float*)d_in[15];
    const float* g1W = (const float*)d_in[16];
    const float* g1as = (const float*)d_in[17];
    const float* g1ad = (const float*)d_in[18];
    const float* g1b = (const float*)d_in[19];
    const float* g2W = (const float*)d_in[20];
    const float* g2as = (const float*)d_in[21];
    const float* g2ad = (const float*)d_in[22];
    const float* g2b = (const float*)d_in[23];
    const float* rW1 = (const float*)d_in[24];
    const float* rb1 = (const float*)d_in[25];
    const float* rW2 = (const float*)d_in[26];
    const float* rb2 = (const float*)d_in[27];
    const float* rW3 = (const float*)d_in[28];
    const float* rb3 = (const float*)d_in[29];

    const int ND = in_sizes[0] / 128;     // 50000
    const int NC = in_sizes[1] / 735;     // 10000
    const int ED = in_sizes[2] / 2;       // 800000
    const int EC = in_sizes[3] / 2;       // 160000
    const int NB = in_sizes[4];           // 16384

    const int* d_src = d_ei;
    const int* d_dst = d_ei + ED;
    const int* c_src = c_ei;
    const int* c_dst = c_ei + EC;

    const size_t MB = 1ull << 20;
    const size_t KB = 1024;
    char* ws = (char*)d_ws;

    // ---- weight split region [0, 9MB) ----
    size_t wo = 0;
    auto walloc = [&](size_t elems) -> unsigned short* {
        unsigned short* p = (unsigned short*)(ws + wo);
        wo += ((elems * 2 + 255) & ~(size_t)255);
        return p;
    };
    unsigned short* dW1h = walloc(256 * 128);  unsigned short* dW1l = walloc(256 * 128);
    unsigned short* cW1h = walloc(1024 * 736); unsigned short* cW1l = walloc(1024 * 736);
    unsigned short* cW2h = walloc(256 * 1024); unsigned short* cW2l = walloc(256 * 1024);
    unsigned short* gdWh = walloc(256 * 256);  unsigned short* gdWl = walloc(256 * 256);
    unsigned short* g1Wh = walloc(1024 * 256); unsigned short* g1Wl = walloc(1024 * 256);
    unsigned short* g2Wh = walloc(256 * 1024); unsigned short* g2Wl = walloc(256 * 1024);
    unsigned short* rW1h = walloc(512 * 512);  unsigned short* rW1l = walloc(512 * 512);
    unsigned short* rW2h = walloc(512 * 512);  unsigned short* rW2l = walloc(512 * 512);

    // ---- small scratch [9, 16MB) ----
    float* wa_ds  = (float*)(ws + 9 * MB);
    float* wa_dd  = (float*)(ws + 9 * MB + 4 * KB);
    float* wa_c1s = (float*)(ws + 9 * MB + 8 * KB);
    float* wa_c1d = (float*)(ws + 9 * MB + 12 * KB);
    float* cas    = (float*)(ws + 9 * MB + 64 * KB);
    float* cad    = (float*)(ws + 9 * MB + 128 * KB);
    int*   coff   = (int*)(ws + 9 * MB + 192 * KB);
    int*   ccur   = (int*)(ws + 9 * MB + 256 * KB);
    int*   ccnt   = (int*)(ws + 9 * MB + 320 * KB);
    int*   bsum_d = (int*)(ws + 9 * MB + 400 * KB);   // 196 ints
    int*   bpre_d = (int*)(ws + 9 * MB + 404 * KB);
    int*   bsum_c = (int*)(ws + 9 * MB + 408 * KB);   // 40 ints
    int*   bpre_c = (int*)(ws + 9 * MB + 412 * KB);
    int*   cebuf  = (int*)(ws + 10 * MB);              // EC+NC ints
    float* das    = (float*)(ws + 11 * MB);
    float* dad    = (float*)(ws + 11 * MB + 256 * KB);
    int*   doff   = (int*)(ws + 11 * MB + 512 * KB);
    int*   dcur   = (int*)(ws + 11 * MB + 768 * KB);
    int*   dcnt   = (int*)(ws + 12 * MB);
    int*   debuf  = (int*)(ws + 12 * MB + 256 * KB);   // ED+ND ints -> ends ~15.7MB

    // ---- big buffers (liveness-checked) ----
    float* dbuf  = (float*)(ws + 16 * MB);                    // d0 [ND,256] [16,65)
    unsigned short* aggdh = (unsigned short*)(ws + 66 * MB);  // [NB,256] [66,74)
    unsigned short* aggdl = (unsigned short*)(ws + 75 * MB);  // [75,83)
    unsigned short* combh = (unsigned short*)(ws + 84 * MB);  // [NB,512] [84,100)
    unsigned short* combl = (unsigned short*)(ws + 101 * MB); // [101,117)
    unsigned short* c0h = (unsigned short*)(ws + 16 * MB);    // [10112,1024] [16,36)  (dbuf dead)
    unsigned short* c0l = (unsigned short*)(ws + 36 * MB);    // [36,56)
    float* c1b   = (float*)(ws + 118 * MB);                   // [NC,256] [118,128)
    unsigned short* aggch = (unsigned short*)(ws + 129 * MB); // [10112,256] [129,134.1)
    unsigned short* aggcl = (unsigned short*)(ws + 135 * MB); // [135,140.1)
    unsigned short* c2h = (unsigned short*)(ws + 16 * MB);    // [16,36)  (c0 dead)
    unsigned short* c2l = (unsigned short*)(ws + 36 * MB);    // [36,56)
    float* xc2   = (float*)(ws + 118 * MB);                   // [118,128) (c1 dead)
    float* cfin  = (float*)(ws + 141 * MB);                   // [141,151)
    unsigned short* h1h = (unsigned short*)(ws + 16 * MB);    // [NB,512] [16,32) (c2 dead)
    unsigned short* h1l = (unsigned short*)(ws + 33 * MB);    // [33,49)
    float* h2b   = (float*)(ws + 50 * MB);                    // [NB,512] fp32 [50,82)
    // cell_x split planes [NC pad 10112][736]
    unsigned short* cxh = (unsigned short*)(ws + 152 * MB);   // [152,166.9)
    unsigned short* cxl = (unsigned short*)(ws + 167 * MB);   // [167,181.9)

    // ================= fused prepass: 8 splits + 4 matvecs ===================
    SJobs js;
    js.j[0] = {dW1, dW1h, dW1l, 128, 256, 128, 0};
    js.j[1] = {cW1, cW1h, cW1l, 735, 1024, 736, 32};
    js.j[2] = {cW2, cW2h, cW2l, 1024, 256, 1024, 768};
    js.j[3] = {gdW, gdWh, gdWl, 256, 256, 256, 1024};
    js.j[4] = {g1W, g1Wh, g1Wl, 256, 1024, 256, 1088};
    js.j[5] = {g2W, g2Wh, g2Wl, 1024, 256, 1024, 1344};
    js.j[6] = {rW1, rW1h, rW1l, 512, 512, 512, 1600};
    js.j[7] = {rW2, rW2h, rW2l, 512, 512, 512, 1856};
    split_transpose_multi<<<2112, 256, 0, stream>>>(js);
    split_cell_rows<<<NC, 256, 0, stream>>>(cell_x, cxh, cxl, NC);
    matvec4<<<1024, 256, 0, stream>>>(gdW, gdas, gdad, wa_ds, wa_dd,
                                      g1W, g1as, g1ad, wa_c1s, wa_c1d);

    // ======================= drug path (batch-sparse) =======================
    hipMemsetAsync(das, 0, (size_t)ND * 4, stream);
    hipMemsetAsync(dad, 0, (size_t)ND * 4, stream);
    {
        int nblk = 2 * ((ND + 63) / 64);
        gemm_d0_fused<<<nblk, 256, 0, stream>>>(
            drug_x, dW1h, dW1l, db1, wa_ds, wa_dd, dbuf, das, dad, ND, nblk);
    }
    hipMemsetAsync(dcnt, 0, (size_t)ND * 4, stream);
    {
        int tot = ED + ND;
        int nbd = (ND + 255) / 256;
        hist_kernel<<<(tot + 255) / 256, 256, 0, stream>>>(d_dst, dcnt, ED, ND);
        scan1_kernel<<<nbd, 256, 0, stream>>>(dcnt, doff, bsum_d, ND);
        scan2_kernel<<<1, 256, 0, stream>>>(bsum_d, bpre_d, nbd, doff, ND);
        scan3_kernel<<<nbd, 256, 0, stream>>>(doff, dcur, bpre_d, ND);
        scatter_kernel<<<(tot + 255) / 256, 256, 0, stream>>>(d_src, d_dst, dcur, debuf, ED, ND);
        gat_agg2<0><<<NB, 256, 0, stream>>>(doff, debuf, das, dad, dbuf, nullptr,
                                            d_idx, nullptr, aggdh, aggdl);
    }
    // comb left half = relu(aggd_batch @ gdW + gdb) as split planes (stride 512)
    gemm2<1, 1><<<mfma_grid64(NB, 256), 256, 0, stream>>>(
        aggdh, aggdl, gdWh, gdWl, gdb, nullptr, combh, combl,
        NB, 256, 256, 256, 512);

    // ======================= cell path =======================
    gemm2<1, 1><<<mfma_grid64(NC, 1024), 256, 0, stream>>>(
        cxh, cxl, cW1h, cW1l, cb1, nullptr, c0h, c0l,
        NC, 736, 1024, 736, 1024);
    gemm2<1, 0><<<mfma_grid64(NC, 256), 256, 0, stream>>>(
        c0h, c0l, cW2h, cW2l, cb2, c1b, nullptr, nullptr,
        NC, 1024, 256, 1024, 256);
    att_scalars<<<NC, 256, 0, stream>>>(c1b, wa_c1s, wa_c1d, cas, cad, 256);
    hipMemsetAsync(ccnt, 0, (size_t)NC * 4, stream);
    {
        int tot = EC + NC;
        int nbc = (NC + 255) / 256;
        hist_kernel<<<(tot + 255) / 256, 256, 0, stream>>>(c_dst, ccnt, EC, NC);
        scan1_kernel<<<nbc, 256, 0, stream>>>(ccnt, coff, bsum_c, NC);
        scan2_kernel<<<1, 256, 0, stream>>>(bsum_c, bpre_c, nbc, coff, NC);
        scan3_kernel<<<nbc, 256, 0, stream>>>(coff, ccur, bpre_c, NC);
        scatter_kernel<<<(tot + 255) / 256, 256, 0, stream>>>(c_src, c_dst, ccur, cebuf, EC, NC);
        gat_agg2<0><<<NC, 256, 0, stream>>>(coff, cebuf, cas, cad, c1b, nullptr,
                                            nullptr, nullptr, aggch, aggcl);
    }
    gemm2<1, 1><<<mfma_grid64(NC, 1024), 256, 0, stream>>>(
        aggch, aggcl, g1Wh, g1Wl, g1b, nullptr, c2h, c2l,
        NC, 256, 1024, 256, 1024);
    gemm2<0, 0><<<mfma_grid64(NC, 256), 256, 0, stream>>>(
        c2h, c2l, g2Wh, g2Wl, nullptr, xc2, nullptr, nullptr,
        NC, 1024, 256, 1024, 256);
    att_scalars<<<NC, 256, 0, stream>>>(xc2, g2as, g2ad, cas, cad, 256);
    gat_agg2<1><<<NC, 256, 0, stream>>>(coff, cebuf, cas, cad, xc2, g2b,
                                        nullptr, cfin, nullptr, nullptr);

    // ======================= head =======================
    gather_cell_split<<<NB, 256, 0, stream>>>(cfin, c_idx, combh, combl);
    gemm2<2, 1><<<mfma_grid64(NB, 512), 256, 0, stream>>>(
        combh, combl, rW1h, rW1l, rb1, nullptr, h1h, h1l,
        NB, 512, 512, 512, 512);
    gemm2<2, 0><<<mfma_grid64(NB, 512), 256, 0, stream>>>(
        h1h, h1l, rW2h, rW2l, rb2, h2b, nullptr, nullptr,
        NB, 512, 512, 512, 512);
    head_final_kernel<<<(NB + 3) / 4, 256, 0, stream>>>(h2b, rW3, rb3, (float*)d_out, NB);
}